// Round 1
// baseline (1821.759 us; speedup 1.0000x reference)
//
#include <hip/hip_runtime.h>
#include <hip/hip_bf16.h>

// Problem constants (B=2, S=2048, D=2048, H=16, dk=128)
#define SEQ   2048
#define DIM   2048
#define NH    16
#define DKH   128
#define BATCH 2
#define MROWS (BATCH * SEQ)   // 4096

using bf16 = __hip_bfloat16;
typedef __attribute__((ext_vector_type(8))) short short8;
typedef __attribute__((ext_vector_type(4))) float floatx4;

// ---------------- cast fp32 -> bf16 (4 elems / thread) ----------------
__global__ __launch_bounds__(256) void cast_kernel(const float* __restrict__ src,
                                                   bf16* __restrict__ dst, int n4) {
  int i = blockIdx.x * 256 + threadIdx.x;
  if (i >= n4) return;
  float4 v = reinterpret_cast<const float4*>(src)[i];
  __hip_bfloat162 h01, h23;
  h01.x = __float2bfloat16(v.x); h01.y = __float2bfloat16(v.y);
  h23.x = __float2bfloat16(v.z); h23.y = __float2bfloat16(v.w);
  reinterpret_cast<__hip_bfloat162*>(dst)[i * 2 + 0] = h01;
  reinterpret_cast<__hip_bfloat162*>(dst)[i * 2 + 1] = h23;
}

// ---------------- bf16 MFMA GEMM: C(MxN) = A(MxK) @ Bw(NxK)^T ----------------
// m93-style: 128x128 tile, BK=32, 4 waves each computing a 64x64 quadrant
// as 4x4 MFMA 16x16x32 tiles. LDS rows padded to 40 bf16 (80B) -> 2-way-max
// bank aliasing on ds_read_b128 (free per m136).
__global__ __launch_bounds__(256) void gemm_bt(const bf16* __restrict__ A,
                                               const bf16* __restrict__ Bw,
                                               float* __restrict__ C,
                                               int M, int N, int K) {
  __shared__ bf16 As[128 * 40];
  __shared__ bf16 Bs[128 * 40];
  const int t = threadIdx.x;
  const int m0 = blockIdx.y * 128;
  const int n0 = blockIdx.x * 128;
  const int w = t >> 6, lane = t & 63;
  const int wm = (w >> 1) * 64, wn = (w & 1) * 64;
  const int lr = lane & 15, quad = lane >> 4;
  const int sq = t & 3, sr = t >> 2;  // staging: 4 threads x 16B per row

  floatx4 acc[4][4];
#pragma unroll
  for (int i = 0; i < 4; ++i)
#pragma unroll
    for (int j = 0; j < 4; ++j)
      acc[i][j] = (floatx4){0.f, 0.f, 0.f, 0.f};

  for (int k0 = 0; k0 < K; k0 += 32) {
    int4 a0 = *reinterpret_cast<const int4*>(A + (size_t)(m0 + sr) * K + k0 + sq * 8);
    int4 a1 = *reinterpret_cast<const int4*>(A + (size_t)(m0 + sr + 64) * K + k0 + sq * 8);
    int4 b0 = *reinterpret_cast<const int4*>(Bw + (size_t)(n0 + sr) * K + k0 + sq * 8);
    int4 b1 = *reinterpret_cast<const int4*>(Bw + (size_t)(n0 + sr + 64) * K + k0 + sq * 8);
    *reinterpret_cast<int4*>(As + sr * 40 + sq * 8) = a0;
    *reinterpret_cast<int4*>(As + (sr + 64) * 40 + sq * 8) = a1;
    *reinterpret_cast<int4*>(Bs + sr * 40 + sq * 8) = b0;
    *reinterpret_cast<int4*>(Bs + (sr + 64) * 40 + sq * 8) = b1;
    __syncthreads();

    short8 af[4], bfr[4];
#pragma unroll
    for (int i = 0; i < 4; ++i)
      af[i] = *reinterpret_cast<const short8*>(As + (wm + i * 16 + lr) * 40 + quad * 8);
#pragma unroll
    for (int j = 0; j < 4; ++j)
      bfr[j] = *reinterpret_cast<const short8*>(Bs + (wn + j * 16 + lr) * 40 + quad * 8);
#pragma unroll
    for (int i = 0; i < 4; ++i)
#pragma unroll
      for (int j = 0; j < 4; ++j)
        acc[i][j] = __builtin_amdgcn_mfma_f32_16x16x32_bf16(af[i], bfr[j], acc[i][j], 0, 0, 0);
    __syncthreads();
  }

  // C/D layout (m89-verified): col = lane&15, row = quad*4 + reg
#pragma unroll
  for (int i = 0; i < 4; ++i)
#pragma unroll
    for (int j = 0; j < 4; ++j) {
      int mrow = m0 + wm + i * 16 + quad * 4;
      int ncol = n0 + wn + j * 16 + lr;
#pragma unroll
      for (int rr = 0; rr < 4; ++rr)
        C[(size_t)(mrow + rr) * N + ncol] = acc[i][j][rr];
    }
}

// ---------------- RoPE in-place on (B,S,H,dk) fp32, interleaved pairs ----------------
__global__ __launch_bounds__(256) void rope_kernel(float* __restrict__ buf,
                                                   const float* __restrict__ cosT,
                                                   const float* __restrict__ sinT,
                                                   int npairs) {
  int g = blockIdx.x * 256 + threadIdx.x;
  if (g >= npairs) return;
  int p = g & 63;                 // pair index within head (dk/2 = 64)
  int r = g >> 6;                 // row = (b*S+s)*H + h
  int s = (r >> 4) & (SEQ - 1);   // r/H % S   (H=16, S=2048 pow2)
  float2 v = reinterpret_cast<float2*>(buf)[g];
  float c = cosT[s * 64 + p];
  float sn = sinT[s * 64 + p];
  float2 o;
  o.x = v.x * c - v.y * sn;
  o.y = v.x * sn + v.y * c;
  reinterpret_cast<float2*>(buf)[g] = o;
}

// ---------------- fp32 flash attention (online softmax) ----------------
// Block = 256 threads handles (b, h, 32-row q tile). Thread (qg=t>>3, kg=t&7):
// scores for q row qg vs keys kg+8u (u=0..3); O cols float4 idx kg+8u.
// Row softmax state replicated across the 8 lanes of each qg group (width-8 shfl).
// LDS row stride 132 floats: K/V float4 reads land on distinct banks.
__global__ __launch_bounds__(256) void attn_kernel(const float* __restrict__ Qf,
                                                   const float* __restrict__ Kf,
                                                   const float* __restrict__ Vf,
                                                   bf16* __restrict__ ctx) {
  const int qt = blockIdx.x;  // 0..63
  const int h = blockIdx.y;
  const int b = blockIdx.z;
  const int t = threadIdx.x;
  const int qg = t >> 3;  // 0..31
  const int kg = t & 7;   // 0..7

  __shared__ float Qs[32 * 132];
  __shared__ float Ks[32 * 132];
  __shared__ float Vs[32 * 132];

  const float scale = 0.08838834764831845f;  // 1/sqrt(128)

  // stage Q tile (pre-scaled)
  {
    int row = t >> 3;
    const float4* src = reinterpret_cast<const float4*>(
        Qf + ((size_t)(b * SEQ + qt * 32 + row) * NH + h) * DKH);
    float4* dstrow = reinterpret_cast<float4*>(Qs + row * 132);
#pragma unroll
    for (int u = 0; u < 4; ++u) {
      float4 v = src[(t & 7) + 8 * u];
      v.x *= scale; v.y *= scale; v.z *= scale; v.w *= scale;
      dstrow[(t & 7) + 8 * u] = v;
    }
  }

  float4 o[4];
#pragma unroll
  for (int u = 0; u < 4; ++u) o[u] = make_float4(0.f, 0.f, 0.f, 0.f);
  float mi = -1e30f, li = 0.f;
  const int qglob = qt * 32 + qg;

  for (int kt = 0; kt <= qt; ++kt) {
    // stage K,V tiles
    {
      int row = t >> 3;
      const float4* ksrc = reinterpret_cast<const float4*>(
          Kf + ((size_t)(b * SEQ + kt * 32 + row) * NH + h) * DKH);
      const float4* vsrc = reinterpret_cast<const float4*>(
          Vf + ((size_t)(b * SEQ + kt * 32 + row) * NH + h) * DKH);
      float4* kd = reinterpret_cast<float4*>(Ks + row * 132);
      float4* vd = reinterpret_cast<float4*>(Vs + row * 132);
#pragma unroll
      for (int u = 0; u < 4; ++u) {
        kd[(t & 7) + 8 * u] = ksrc[(t & 7) + 8 * u];
        vd[(t & 7) + 8 * u] = vsrc[(t & 7) + 8 * u];
      }
    }
    __syncthreads();

    // scores: s[u] = q(qg) . k(kg+8u)
    float s0 = 0.f, s1 = 0.f, s2 = 0.f, s3 = 0.f;
    {
      const float4* Q4 = reinterpret_cast<const float4*>(Qs + qg * 132);
      const float4* K4 = reinterpret_cast<const float4*>(Ks);
#pragma unroll 4
      for (int d4 = 0; d4 < 32; ++d4) {
        float4 qv = Q4[d4];
        float4 k0 = K4[(kg + 0) * 33 + d4];
        float4 k1 = K4[(kg + 8) * 33 + d4];
        float4 k2 = K4[(kg + 16) * 33 + d4];
        float4 k3 = K4[(kg + 24) * 33 + d4];
        s0 += qv.x * k0.x + qv.y * k0.y + qv.z * k0.z + qv.w * k0.w;
        s1 += qv.x * k1.x + qv.y * k1.y + qv.z * k1.z + qv.w * k1.w;
        s2 += qv.x * k2.x + qv.y * k2.y + qv.z * k2.z + qv.w * k2.w;
        s3 += qv.x * k3.x + qv.y * k3.y + qv.z * k3.z + qv.w * k3.w;
      }
    }
    // causal mask: only the diagonal tile needs it
    if (kt == qt) {
      if (kg + 0 > qg) s0 = -1e9f;
      if (kg + 8 > qg) s1 = -1e9f;
      if (kg + 16 > qg) s2 = -1e9f;
      if (kg + 24 > qg) s3 = -1e9f;
    }

    // online softmax across the 8-lane row group
    float mx = fmaxf(fmaxf(s0, s1), fmaxf(s2, s3));
    mx = fmaxf(mx, __shfl_xor(mx, 1, 8));
    mx = fmaxf(mx, __shfl_xor(mx, 2, 8));
    mx = fmaxf(mx, __shfl_xor(mx, 4, 8));
    float mnew = fmaxf(mi, mx);
    float alpha = __expf(mi - mnew);
    float p[4];
    p[0] = __expf(s0 - mnew);
    p[1] = __expf(s1 - mnew);
    p[2] = __expf(s2 - mnew);
    p[3] = __expf(s3 - mnew);
    float rs = p[0] + p[1] + p[2] + p[3];
    rs += __shfl_xor(rs, 1, 8);
    rs += __shfl_xor(rs, 2, 8);
    rs += __shfl_xor(rs, 4, 8);
    li = li * alpha + rs;
    mi = mnew;
#pragma unroll
    for (int u = 0; u < 4; ++u) {
      o[u].x *= alpha; o[u].y *= alpha; o[u].z *= alpha; o[u].w *= alpha;
    }

    // O += P @ V   (key j owned by lane jj=j&7, register uj=j>>3)
    {
      const float4* V4 = reinterpret_cast<const float4*>(Vs);
#pragma unroll
      for (int uj = 0; uj < 4; ++uj) {
#pragma unroll
        for (int jj = 0; jj < 8; ++jj) {
          float pj = __shfl(p[uj], jj, 8);
          int j = uj * 8 + jj;
#pragma unroll
          for (int u = 0; u < 4; ++u) {
            float4 vv = V4[j * 33 + kg + 8 * u];
            o[u].x += pj * vv.x; o[u].y += pj * vv.y;
            o[u].z += pj * vv.z; o[u].w += pj * vv.w;
          }
        }
      }
    }
    __syncthreads();
  }

  // epilogue: normalize and store ctx as bf16 (layout (B,S,H*dk) == MxD)
  float inv = 1.0f / li;
  size_t mrow = (size_t)b * SEQ + qt * 32 + qg;
  bf16* dst = ctx + mrow * DIM + h * DKH;
#pragma unroll
  for (int u = 0; u < 4; ++u) {
    int c = (kg + 8 * u) * 4;
    dst[c + 0] = __float2bfloat16(o[u].x * inv);
    dst[c + 1] = __float2bfloat16(o[u].y * inv);
    dst[c + 2] = __float2bfloat16(o[u].z * inv);
    dst[c + 3] = __float2bfloat16(o[u].w * inv);
  }
}

// ---------------- launch ----------------
extern "C" void kernel_launch(void* const* d_in, const int* in_sizes, int n_in,
                              void* d_out, int out_size, void* d_ws, size_t ws_size,
                              hipStream_t stream) {
  const float* x = (const float*)d_in[0];
  const float* fcos = (const float*)d_in[1];
  const float* fsin = (const float*)d_in[2];
  // d_in[3] = mask (unused; causal applied analytically, matches -1e9 mask)
  const float* Wq = (const float*)d_in[4];
  const float* Wk = (const float*)d_in[5];
  const float* Wv = (const float*)d_in[6];
  const float* Wo = (const float*)d_in[7];

  float* out = (float*)d_out;                     // M x D
  float* Kout = out + (size_t)MROWS * DIM;        // M x D (K cache, post-RoPE)
  float* Vout = Kout + (size_t)MROWS * DIM;       // M x D (V cache)

  // workspace layout (~96 MB)
  bf16* xb = (bf16*)d_ws;                          // M*D bf16
  bf16* Wqb = xb + (size_t)MROWS * DIM;            // D*D bf16 each
  bf16* Wkb = Wqb + (size_t)DIM * DIM;
  bf16* Wvb = Wkb + (size_t)DIM * DIM;
  bf16* Wob = Wvb + (size_t)DIM * DIM;
  float* Qf = (float*)(Wob + (size_t)DIM * DIM);   // M*D fp32
  bf16* ctxb = (bf16*)(Qf + (size_t)MROWS * DIM);  // M*D bf16

  const int nXD4 = MROWS * DIM / 4;  // 2,097,152
  const int nWD4 = DIM * DIM / 4;    // 1,048,576
  cast_kernel<<<nXD4 / 256, 256, 0, stream>>>(x, xb, nXD4);
  cast_kernel<<<nWD4 / 256, 256, 0, stream>>>(Wq, Wqb, nWD4);
  cast_kernel<<<nWD4 / 256, 256, 0, stream>>>(Wk, Wkb, nWD4);
  cast_kernel<<<nWD4 / 256, 256, 0, stream>>>(Wv, Wvb, nWD4);
  cast_kernel<<<nWD4 / 256, 256, 0, stream>>>(Wo, Wob, nWD4);

  dim3 gg(DIM / 128, MROWS / 128);  // (16, 32)
  gemm_bt<<<gg, 256, 0, stream>>>(xb, Wqb, Qf, MROWS, DIM, DIM);
  gemm_bt<<<gg, 256, 0, stream>>>(xb, Wkb, Kout, MROWS, DIM, DIM);
  gemm_bt<<<gg, 256, 0, stream>>>(xb, Wvb, Vout, MROWS, DIM, DIM);

  const int npairs = MROWS * NH * (DKH / 2);  // 4,194,304
  rope_kernel<<<npairs / 256, 256, 0, stream>>>(Qf, fcos, fsin, npairs);
  rope_kernel<<<npairs / 256, 256, 0, stream>>>(Kout, fcos, fsin, npairs);

  dim3 ga(SEQ / 32, NH, BATCH);  // (64, 16, 2)
  attn_kernel<<<ga, 256, 0, stream>>>(Qf, Kout, Vout, ctxb);

  gemm_bt<<<gg, 256, 0, stream>>>(ctxb, Wob, out, MROWS, DIM, DIM);
}

// Round 2
// 735.481 us; speedup vs baseline: 2.4770x; 2.4770x over previous
//
#include <hip/hip_runtime.h>
#include <hip/hip_bf16.h>

// Problem constants (B=2, S=2048, D=2048, H=16, dk=128)
#define SEQ   2048
#define DIM   2048
#define NH    16
#define DKH   128
#define BATCH 2
#define MROWS (BATCH * SEQ)   // 4096

using bf16 = __hip_bfloat16;
typedef __attribute__((ext_vector_type(8))) short short8;
typedef __attribute__((ext_vector_type(4))) short short4v;
typedef __attribute__((ext_vector_type(4))) float floatx4;

union BfBits { bf16 h; short s; };

// ---------------- cast fp32 -> bf16 (4 elems / thread) ----------------
__global__ __launch_bounds__(256) void cast_kernel(const float* __restrict__ src,
                                                   bf16* __restrict__ dst, int n4) {
  int i = blockIdx.x * 256 + threadIdx.x;
  if (i >= n4) return;
  float4 v = reinterpret_cast<const float4*>(src)[i];
  __hip_bfloat162 h01, h23;
  h01.x = __float2bfloat16(v.x); h01.y = __float2bfloat16(v.y);
  h23.x = __float2bfloat16(v.z); h23.y = __float2bfloat16(v.w);
  reinterpret_cast<__hip_bfloat162*>(dst)[i * 2 + 0] = h01;
  reinterpret_cast<__hip_bfloat162*>(dst)[i * 2 + 1] = h23;
}

// ---------------- bf16 MFMA GEMM: C(MxN) = A(MxK) @ Bw(NxK)^T ----------------
template <typename CT>
__global__ __launch_bounds__(256) void gemm_bt(const bf16* __restrict__ A,
                                               const bf16* __restrict__ Bw,
                                               CT* __restrict__ C,
                                               int M, int N, int K) {
  __shared__ bf16 As[128 * 40];
  __shared__ bf16 Bs[128 * 40];
  const int t = threadIdx.x;
  const int m0 = blockIdx.y * 128;
  const int n0 = blockIdx.x * 128;
  const int w = t >> 6, lane = t & 63;
  const int wm = (w >> 1) * 64, wn = (w & 1) * 64;
  const int lr = lane & 15, quad = lane >> 4;
  const int sq = t & 3, sr = t >> 2;

  floatx4 acc[4][4];
#pragma unroll
  for (int i = 0; i < 4; ++i)
#pragma unroll
    for (int j = 0; j < 4; ++j)
      acc[i][j] = (floatx4){0.f, 0.f, 0.f, 0.f};

  for (int k0 = 0; k0 < K; k0 += 32) {
    int4 a0 = *reinterpret_cast<const int4*>(A + (size_t)(m0 + sr) * K + k0 + sq * 8);
    int4 a1 = *reinterpret_cast<const int4*>(A + (size_t)(m0 + sr + 64) * K + k0 + sq * 8);
    int4 b0 = *reinterpret_cast<const int4*>(Bw + (size_t)(n0 + sr) * K + k0 + sq * 8);
    int4 b1 = *reinterpret_cast<const int4*>(Bw + (size_t)(n0 + sr + 64) * K + k0 + sq * 8);
    *reinterpret_cast<int4*>(As + sr * 40 + sq * 8) = a0;
    *reinterpret_cast<int4*>(As + (sr + 64) * 40 + sq * 8) = a1;
    *reinterpret_cast<int4*>(Bs + sr * 40 + sq * 8) = b0;
    *reinterpret_cast<int4*>(Bs + (sr + 64) * 40 + sq * 8) = b1;
    __syncthreads();

    short8 af[4], bfr[4];
#pragma unroll
    for (int i = 0; i < 4; ++i)
      af[i] = *reinterpret_cast<const short8*>(As + (wm + i * 16 + lr) * 40 + quad * 8);
#pragma unroll
    for (int j = 0; j < 4; ++j)
      bfr[j] = *reinterpret_cast<const short8*>(Bs + (wn + j * 16 + lr) * 40 + quad * 8);
#pragma unroll
    for (int i = 0; i < 4; ++i)
#pragma unroll
      for (int j = 0; j < 4; ++j)
        acc[i][j] = __builtin_amdgcn_mfma_f32_16x16x32_bf16(af[i], bfr[j], acc[i][j], 0, 0, 0);
    __syncthreads();
  }

#pragma unroll
  for (int i = 0; i < 4; ++i)
#pragma unroll
    for (int j = 0; j < 4; ++j) {
      int mrow = m0 + wm + i * 16 + quad * 4;
      int ncol = n0 + wn + j * 16 + lr;
#pragma unroll
      for (int rr = 0; rr < 4; ++rr) {
        if constexpr (__is_same(CT, float))
          C[(size_t)(mrow + rr) * N + ncol] = acc[i][j][rr];
        else
          C[(size_t)(mrow + rr) * N + ncol] = __float2bfloat16(acc[i][j][rr]);
      }
    }
}

// ---------------- RoPE Q: bf16 (B,S,D) -> bf16 (B,H,S,dk) ----------------
__global__ __launch_bounds__(256) void rope_q(const bf16* __restrict__ Qraw,
                                              const float* __restrict__ cosT,
                                              const float* __restrict__ sinT,
                                              bf16* __restrict__ Qb) {
  int g = blockIdx.x * 256 + threadIdx.x;  // pair index, < M*D/2
  int p = g & 63;
  int r = g >> 6;                 // (b*S+s)*16 + h
  int h = r & 15;
  int s = (r >> 4) & (SEQ - 1);
  int b = r >> 15;
  __hip_bfloat162 v = reinterpret_cast<const __hip_bfloat162*>(Qraw)[g];
  float x0 = __bfloat162float(v.x), x1 = __bfloat162float(v.y);
  float c = cosT[s * 64 + p], sn = sinT[s * 64 + p];
  __hip_bfloat162 o;
  o.x = __float2bfloat16(x0 * c - x1 * sn);
  o.y = __float2bfloat16(x0 * sn + x1 * c);
  reinterpret_cast<__hip_bfloat162*>(Qb)[((size_t)(b * NH + h) * SEQ + s) * 64 + p] = o;
}

// ---------------- RoPE K: fp32 (B,S,D) in-place + bf16 (B,H,S,dk) ----------------
__global__ __launch_bounds__(256) void rope_k(float* __restrict__ Kf,
                                              const float* __restrict__ cosT,
                                              const float* __restrict__ sinT,
                                              bf16* __restrict__ Kb) {
  int g = blockIdx.x * 256 + threadIdx.x;
  int p = g & 63;
  int r = g >> 6;
  int h = r & 15;
  int s = (r >> 4) & (SEQ - 1);
  int b = r >> 15;
  float2 v = reinterpret_cast<const float2*>(Kf)[g];
  float c = cosT[s * 64 + p], sn = sinT[s * 64 + p];
  float o0 = v.x * c - v.y * sn;
  float o1 = v.x * sn + v.y * c;
  reinterpret_cast<float2*>(Kf)[g] = make_float2(o0, o1);
  __hip_bfloat162 ob;
  ob.x = __float2bfloat16(o0);
  ob.y = __float2bfloat16(o1);
  reinterpret_cast<__hip_bfloat162*>(Kb)[((size_t)(b * NH + h) * SEQ + s) * 64 + p] = ob;
}

// ---------------- V transpose: fp32 (B,S,D) -> bf16 (B,H,dk,S) ----------------
__global__ __launch_bounds__(256) void vt_kernel(const float* __restrict__ V,
                                                 bf16* __restrict__ Vt) {
  __shared__ float tile[32][33];
  const int s0 = blockIdx.x * 32;
  const int d0 = blockIdx.y * 32;
  const int bh = blockIdx.z;
  const int b = bh >> 4, h = bh & 15;
  const int t = threadIdx.x;
  const int row = t >> 3, c4 = (t & 7) * 4;

  float4 v = *reinterpret_cast<const float4*>(
      V + (size_t)(b * SEQ + s0 + row) * DIM + h * DKH + d0 + c4);
  tile[row][c4 + 0] = v.x; tile[row][c4 + 1] = v.y;
  tile[row][c4 + 2] = v.z; tile[row][c4 + 3] = v.w;
  __syncthreads();

  short4v ov;
#pragma unroll
  for (int i = 0; i < 4; ++i) {
    BfBits u; u.h = __float2bfloat16(tile[c4 + i][row]);
    ov[i] = u.s;
  }
  *reinterpret_cast<short4v*>(Vt + ((size_t)(b * NH + h) * DKH + d0 + row) * SEQ + s0 + c4) = ov;
}

// ---------------- MFMA flash attention ----------------
// Block: 256 thr = 4 waves, one (b,h), BQ=64 q rows (wave w -> rows w*16..+15).
// K tiles BK=64. Layouts (verified m89/m120):
//   A-frag:  A[m=lane&15][k=quad*8+j]
//   B-frag:  B[n=lane&15(+16*tile)][k=quad*8+j]
//   C/D:     col=lane&15, row=quad*4+reg
__global__ __launch_bounds__(256) void attn_mfma(const bf16* __restrict__ Qb,
                                                 const bf16* __restrict__ Kb,
                                                 const bf16* __restrict__ Vt,
                                                 bf16* __restrict__ ctx) {
  const int qt = (SEQ / 64 - 1) - blockIdx.x;  // reversed: heavy blocks first
  const int h = blockIdx.y;
  const int b = blockIdx.z;
  const int t = threadIdx.x;
  const int w = t >> 6, lane = t & 63;
  const int lr = lane & 15, quad = lane >> 4;

  __shared__ short Ks[64 * 136];   // K tile rows padded 128->136
  __shared__ short Vs[128 * 72];   // Vt tile rows padded 64->72
  __shared__ short Ps[4 * 16 * 72];  // per-wave P strips

  const float scale = 0.08838834764831845f;  // 1/sqrt(128)
  const size_t headQK = (size_t)(b * NH + h) * SEQ * DKH;

  // Q fragments for this wave's 16-row strip (resident across all kt)
  short8 qa[4];
  {
    const short* qbase = (const short*)Qb + headQK + (size_t)(qt * 64 + w * 16 + lr) * DKH;
#pragma unroll
    for (int kk = 0; kk < 4; ++kk)
      qa[kk] = *reinterpret_cast<const short8*>(qbase + kk * 32 + quad * 8);
  }

  floatx4 o[8];
#pragma unroll
  for (int n = 0; n < 8; ++n) o[n] = (floatx4){0.f, 0.f, 0.f, 0.f};
  float m[4] = {-1e30f, -1e30f, -1e30f, -1e30f};
  float l[4] = {0.f, 0.f, 0.f, 0.f};

  for (int kt = 0; kt <= qt; ++kt) {
    // stage K tile (contiguous 16 KB in global)
    {
      const short* kbase = (const short*)Kb + headQK + (size_t)(kt * 64) * DKH;
#pragma unroll
      for (int u = 0; u < 4; ++u) {
        int c = t + 256 * u;
        *reinterpret_cast<int4*>(Ks + (c >> 4) * 136 + (c & 15) * 8) =
            *reinterpret_cast<const int4*>(kbase + c * 8);
      }
      const short* vbase = (const short*)Vt + (size_t)(b * NH + h) * DKH * SEQ + kt * 64;
#pragma unroll
      for (int u = 0; u < 4; ++u) {
        int c = t + 256 * u;
        *reinterpret_cast<int4*>(Vs + (c >> 3) * 72 + (c & 7) * 8) =
            *reinterpret_cast<const int4*>(vbase + (size_t)(c >> 3) * SEQ + (c & 7) * 8);
      }
    }
    __syncthreads();

    // QK^T: S strip 16x64 for this wave
    floatx4 sj[4];
#pragma unroll
    for (int j = 0; j < 4; ++j) sj[j] = (floatx4){0.f, 0.f, 0.f, 0.f};
#pragma unroll
    for (int j = 0; j < 4; ++j)
#pragma unroll
      for (int kk = 0; kk < 4; ++kk) {
        short8 kb = *reinterpret_cast<const short8*>(Ks + (j * 16 + lr) * 136 + kk * 32 + quad * 8);
        sj[j] = __builtin_amdgcn_mfma_f32_16x16x32_bf16(qa[kk], kb, sj[j], 0, 0, 0);
      }

    // scale + causal mask (diagonal tile only)
    float sc[4][4];
#pragma unroll
    for (int j = 0; j < 4; ++j)
#pragma unroll
      for (int r = 0; r < 4; ++r) sc[j][r] = sj[j][r] * scale;
    if (kt == qt) {
#pragma unroll
      for (int j = 0; j < 4; ++j) {
        int col = kt * 64 + j * 16 + lr;
#pragma unroll
        for (int r = 0; r < 4; ++r) {
          int rowg = qt * 64 + w * 16 + quad * 4 + r;
          if (col > rowg) sc[j][r] = -1e9f;
        }
      }
    }

    // online softmax, per row r (row = quad*4+r; cols across lr + j*16)
#pragma unroll
    for (int r = 0; r < 4; ++r) {
      float mx = fmaxf(fmaxf(sc[0][r], sc[1][r]), fmaxf(sc[2][r], sc[3][r]));
      mx = fmaxf(mx, __shfl_xor(mx, 1, 16));
      mx = fmaxf(mx, __shfl_xor(mx, 2, 16));
      mx = fmaxf(mx, __shfl_xor(mx, 4, 16));
      mx = fmaxf(mx, __shfl_xor(mx, 8, 16));
      float mnew = fmaxf(m[r], mx);
      float alpha = __expf(m[r] - mnew);
      float rs = 0.f;
#pragma unroll
      for (int j = 0; j < 4; ++j) {
        float p = __expf(sc[j][r] - mnew);
        rs += p;
        BfBits u; u.h = __float2bfloat16(p);
        Ps[(w * 16 + quad * 4 + r) * 72 + j * 16 + lr] = u.s;
      }
      rs += __shfl_xor(rs, 1, 16);
      rs += __shfl_xor(rs, 2, 16);
      rs += __shfl_xor(rs, 4, 16);
      rs += __shfl_xor(rs, 8, 16);
      l[r] = l[r] * alpha + rs;
      m[r] = mnew;
#pragma unroll
      for (int n = 0; n < 8; ++n) o[n][r] *= alpha;
    }

    // PV: wave-private P strip (no barrier needed; wave LDS ops are ordered)
    short8 pa0 = *reinterpret_cast<const short8*>(Ps + (w * 16 + lr) * 72 + quad * 8);
    short8 pa1 = *reinterpret_cast<const short8*>(Ps + (w * 16 + lr) * 72 + 32 + quad * 8);
#pragma unroll
    for (int n = 0; n < 8; ++n) {
      short8 vb0 = *reinterpret_cast<const short8*>(Vs + (n * 16 + lr) * 72 + quad * 8);
      short8 vb1 = *reinterpret_cast<const short8*>(Vs + (n * 16 + lr) * 72 + 32 + quad * 8);
      o[n] = __builtin_amdgcn_mfma_f32_16x16x32_bf16(pa0, vb0, o[n], 0, 0, 0);
      o[n] = __builtin_amdgcn_mfma_f32_16x16x32_bf16(pa1, vb1, o[n], 0, 0, 0);
    }
    __syncthreads();
  }

  // epilogue: normalize, store ctx (B,S,D) bf16
  float inv[4];
#pragma unroll
  for (int r = 0; r < 4; ++r) inv[r] = 1.0f / l[r];
#pragma unroll
  for (int r = 0; r < 4; ++r) {
    size_t mrow = (size_t)b * SEQ + qt * 64 + w * 16 + quad * 4 + r;
    bf16* dst = ctx + mrow * DIM + h * DKH;
#pragma unroll
    for (int n = 0; n < 8; ++n)
      dst[n * 16 + lr] = __float2bfloat16(o[n][r] * inv[r]);
  }
}

// ---------------- launch ----------------
extern "C" void kernel_launch(void* const* d_in, const int* in_sizes, int n_in,
                              void* d_out, int out_size, void* d_ws, size_t ws_size,
                              hipStream_t stream) {
  const float* x = (const float*)d_in[0];
  const float* fcos = (const float*)d_in[1];
  const float* fsin = (const float*)d_in[2];
  // d_in[3] = mask (causal applied analytically)
  const float* Wq = (const float*)d_in[4];
  const float* Wk = (const float*)d_in[5];
  const float* Wv = (const float*)d_in[6];
  const float* Wo = (const float*)d_in[7];

  float* out = (float*)d_out;                  // M x D
  float* Kout = out + (size_t)MROWS * DIM;     // K cache (fp32, post-RoPE)
  float* Vout = Kout + (size_t)MROWS * DIM;    // V cache (fp32)

  // workspace layout (~117 MB)
  const size_t MD = (size_t)MROWS * DIM;       // 8.39M
  const size_t DD = (size_t)DIM * DIM;         // 4.19M
  bf16* xb   = (bf16*)d_ws;          // MD
  bf16* Wqb  = xb + MD;              // DD x4
  bf16* Wkb  = Wqb + DD;
  bf16* Wvb  = Wkb + DD;
  bf16* Wob  = Wvb + DD;
  bf16* Qraw = Wob + DD;             // MD  (pre-RoPE Q, (B,S,D)); reused as ctxb
  bf16* Qb   = Qraw + MD;            // MD  (post-RoPE, (B,H,S,dk))
  bf16* Kb   = Qb + MD;              // MD  (post-RoPE, (B,H,S,dk))
  bf16* Vt   = Kb + MD;              // MD  ((B,H,dk,S))
  bf16* ctxb = Qraw;                 // alias: Qraw dead after rope_q

  const int nXD4 = MROWS * DIM / 4;
  const int nWD4 = DIM * DIM / 4;
  cast_kernel<<<nXD4 / 256, 256, 0, stream>>>(x, xb, nXD4);
  cast_kernel<<<nWD4 / 256, 256, 0, stream>>>(Wq, Wqb, nWD4);
  cast_kernel<<<nWD4 / 256, 256, 0, stream>>>(Wk, Wkb, nWD4);
  cast_kernel<<<nWD4 / 256, 256, 0, stream>>>(Wv, Wvb, nWD4);
  cast_kernel<<<nWD4 / 256, 256, 0, stream>>>(Wo, Wob, nWD4);

  dim3 gg(DIM / 128, MROWS / 128);  // (16, 32)
  gemm_bt<bf16><<<gg, 256, 0, stream>>>(xb, Wqb, Qraw, MROWS, DIM, DIM);
  gemm_bt<float><<<gg, 256, 0, stream>>>(xb, Wkb, Kout, MROWS, DIM, DIM);
  gemm_bt<float><<<gg, 256, 0, stream>>>(xb, Wvb, Vout, MROWS, DIM, DIM);

  const int npairs = MROWS * DIM / 2;  // 4,194,304
  rope_q<<<npairs / 256, 256, 0, stream>>>(Qraw, fcos, fsin, Qb);
  rope_k<<<npairs / 256, 256, 0, stream>>>(Kout, fcos, fsin, Kb);

  dim3 gv(SEQ / 32, DKH / 32, BATCH * NH);  // (64, 4, 32)
  vt_kernel<<<gv, 256, 0, stream>>>(Vout, Vt);

  dim3 ga(SEQ / 64, NH, BATCH);  // (32, 16, 2)
  attn_mfma<<<ga, 256, 0, stream>>>(Qb, Kb, Vt, ctxb);

  gemm_bt<float><<<gg, 256, 0, stream>>>(ctxb, Wob, out, MROWS, DIM, DIM);
}